// Round 5
// baseline (1288.104 us; speedup 1.0000x reference)
//
#include <hip/hip_runtime.h>
#include <math.h>

#define N_PTS 65536
#define DIM   64
#define K_CL  128
#define EPSV  1e-8f
#define CAP   8192
#define ARENA 8192   // floats per side in the sort arena (64 KB total)

// ---------------- ws layout (bytes) ----------------
// 0                : fill_acc[128] float (atomics; zeroed each launch)
// 512              : loss_acc[1]   float (zeroed each launch)
// 1024             : pred_x[N]     int
// 263168           : idx_x[128*CAP] int
// 263168+4194304   : idx_t[128*CAP] int
// 263168+8388608   : count_x[128] int
// 263168+8388608+512 : count_t[128] int

__global__ __launch_bounds__(256) void k_zero(float* ws_f) {
  ws_f[threadIdx.x] = 0.0f;  // zeros first 1024 B: fill_acc + loss_acc
}

// one thread per point; centers read via wave-uniform (scalarized) global
// loads -> s_load through scalar cache, VALU does pure v_fmac.
__global__ __launch_bounds__(256) void k_pred_fill(
    const float* __restrict__ x, const float* __restrict__ centers,
    float* __restrict__ fill_acc, int* __restrict__ pred_x)
{
  __shared__ float csq[K_CL];
  __shared__ float fill_lds[K_CL];
  const int tid = threadIdx.x;

  if (tid < K_CL) {
    const float* cp = centers + tid * DIM;
    float s = 0.0f;
    #pragma unroll 8
    for (int d = 0; d < DIM; ++d) { float v = cp[d]; s += v * v; }
    csq[tid] = s;
    fill_lds[tid] = 0.0f;
  }

  const int i = blockIdx.x * 256 + tid;
  float xr[DIM];
  const float4* xp = reinterpret_cast<const float4*>(x + (size_t)i * DIM);
  #pragma unroll
  for (int q = 0; q < DIM / 4; ++q) {
    float4 v = xp[q];
    xr[4 * q + 0] = v.x; xr[4 * q + 1] = v.y;
    xr[4 * q + 2] = v.z; xr[4 * q + 3] = v.w;
  }
  float xsq = 0.0f;
  #pragma unroll
  for (int d = 0; d < DIM; ++d) xsq += xr[d] * xr[d];
  __syncthreads();

  // ---- pass 1: sumw + argmin (first-index tie-break via strict <) ----
  float sumw = 0.0f;
  float best = INFINITY;
  int   bestj = 0;
  #pragma unroll 2
  for (int j = 0; j < K_CL; ++j) {
    const float* cp = centers + j * DIM;   // uniform address -> s_load
    float d0 = 0.f, d1 = 0.f, d2a = 0.f, d3 = 0.f;
    #pragma unroll
    for (int d = 0; d < DIM; d += 4) {
      d0  += xr[d + 0] * cp[d + 0];
      d1  += xr[d + 1] * cp[d + 1];
      d2a += xr[d + 2] * cp[d + 2];
      d3  += xr[d + 3] * cp[d + 3];
    }
    float dot  = (d0 + d1) + (d2a + d3);
    float dsq  = xsq + csq[j] - 2.0f * dot;
    float dist = sqrtf(fmaxf(dsq, 0.0f));
    float w    = 1.0f / (dist + EPSV);
    sumw += w;
    if (dist < best) { best = dist; bestj = j; }
  }
  pred_x[i] = bestj;
  const float inv = 1.0f / sumw;
  const int lane = tid & 63;

  // ---- pass 2: normalized weights -> per-cluster sums ----
  #pragma unroll 2
  for (int j = 0; j < K_CL; ++j) {
    const float* cp = centers + j * DIM;   // uniform address -> s_load
    float d0 = 0.f, d1 = 0.f, d2a = 0.f, d3 = 0.f;
    #pragma unroll
    for (int d = 0; d < DIM; d += 4) {
      d0  += xr[d + 0] * cp[d + 0];
      d1  += xr[d + 1] * cp[d + 1];
      d2a += xr[d + 2] * cp[d + 2];
      d3  += xr[d + 3] * cp[d + 3];
    }
    float dot  = (d0 + d1) + (d2a + d3);
    float dsq  = xsq + csq[j] - 2.0f * dot;
    float dist = sqrtf(fmaxf(dsq, 0.0f));
    float wn   = (1.0f / (dist + EPSV)) * inv;
    #pragma unroll
    for (int off = 32; off > 0; off >>= 1) wn += __shfl_down(wn, off);
    if (lane == 0) atomicAdd(&fill_lds[j], wn);
  }
  __syncthreads();
  if (tid < K_CL) atomicAdd(&fill_acc[tid], fill_lds[tid]);
}

// stable (index-ordered) member-list build: one block per (cluster, side)
__global__ __launch_bounds__(1024) void k_scatter(
    const int* __restrict__ pred_x, const int* __restrict__ pred_t,
    int* __restrict__ idx_x, int* __restrict__ idx_t,
    int* __restrict__ count_x, int* __restrict__ count_t)
{
  const int c    = blockIdx.x >> 1;
  const int side = blockIdx.x & 1;
  const int* __restrict__ pred = side ? pred_t : pred_x;
  int* __restrict__ out = side ? idx_t : idx_x;
  int* __restrict__ cnt = side ? count_t : count_x;

  __shared__ int wsum[16];
  const int tid = threadIdx.x, lane = tid & 63, w = tid >> 6;
  int base = 0;
  for (int start = 0; start < N_PTS; start += 1024) {
    const int i = start + tid;                 // N % 1024 == 0
    const bool m = (pred[i] == c);
    unsigned long long bal = __ballot(m);
    int lp = __popcll(bal & ((1ull << lane) - 1ull));
    if (lane == 0) wsum[w] = __popcll(bal);
    __syncthreads();
    int wbase = 0, tot = 0;
    #pragma unroll
    for (int k = 0; k < 16; ++k) { int v = wsum[k]; tot += v; if (k < w) wbase += v; }
    if (m) { int pos = base + wbase + lp; if (pos < CAP) out[c * CAP + pos] = i; }
    base += tot;
    __syncthreads();
  }
  if (tid == 0) cnt[c] = base;
}

// ---- in-register bitonic helpers (8 contiguous elements / thread) ----
__device__ __forceinline__ void ce(float& a, float& b, bool up) {
  float lo = fminf(a, b), hi = fmaxf(a, b);
  a = up ? lo : hi;
  b = up ? hi : lo;
}

__device__ __forceinline__ void merge8(float v[8], bool up) {
  ce(v[0],v[4],up); ce(v[1],v[5],up); ce(v[2],v[6],up); ce(v[3],v[7],up);
  ce(v[0],v[2],up); ce(v[1],v[3],up); ce(v[4],v[6],up); ce(v[5],v[7],up);
  ce(v[0],v[1],up); ce(v[2],v[3],up); ce(v[4],v[5],up); ce(v[6],v[7],up);
}

__device__ __forceinline__ void sort8(float v[8], bool up8) {
  ce(v[0],v[1],true );  ce(v[2],v[3],false); ce(v[4],v[5],true );  ce(v[6],v[7],false);
  ce(v[0],v[2],true );  ce(v[1],v[3],true );  ce(v[4],v[6],false); ce(v[5],v[7],false);
  ce(v[0],v[1],true );  ce(v[2],v[3],true );  ce(v[4],v[5],false); ce(v[6],v[7],false);
  merge8(v, up8);
}

__device__ __forceinline__ float4 sel4(float4 a, float4 b, bool takeA) {
  return takeA ? a : b;
}

// Unified W1 kernel. Block (c, d0) packs F = min(64, ARENA/P) feature
// columns (padded length P) into one 8192-element arena and sorts all
// segments simultaneously. Direction up = ((i & k & (P-1)) == 0) sorts every
// segment ascending, including the final k == P merge. Hybrid bitonic:
// 8 elems/thread in registers, LDS float4 phases for j >= 8.
__global__ __launch_bounds__(1024) void k_w1_u(
    const float* __restrict__ x, const float* __restrict__ t,
    const int* __restrict__ idx_x, const int* __restrict__ idx_t,
    const int* __restrict__ count_x, const int* __restrict__ count_t,
    float* __restrict__ loss_acc)
{
  __shared__ float sa[ARENA];   // 32 KB
  __shared__ float sb[ARENA];   // 32 KB
  __shared__ float red[16];
  const int c  = blockIdx.x >> 6;
  const int d0 = blockIdx.x & 63;
  const int m = min(min(count_x[c], CAP), min(count_t[c], CAP));
  if (m == 0) return;

  int P = 8, lp = 3;
  while (P < m) { P <<= 1; ++lp; }
  const int F = min(64, ARENA >> lp);   // feature columns per block
  if (d0 & (F - 1)) return;             // not a task leader
  const int used = F << lp;             // occupied arena elements

  const int tid  = threadIdx.x;
  const int base = tid << 3;            // chunk of 8 per thread
  const bool own = (base < used);
  const int seg  = base >> lp;          // segment = feature offset
  const int r    = base & (P - 1);      // row within segment
  float va[8], vb[8];

  if (own) {
    const int d  = d0 + seg;
    const int gb = c * CAP + r;
    #pragma unroll
    for (int e = 0; e < 8; ++e) {
      if (r + e < m) {
        va[e] = x[(size_t)idx_x[gb + e] * DIM + d];
        vb[e] = t[(size_t)idx_t[gb + e] * DIM + d];
      } else { va[e] = INFINITY; vb[e] = INFINITY; }
    }
    const bool u8 = ((base & 8 & (P - 1)) == 0);
    sort8(va, u8);
    sort8(vb, u8);
    if (P > 8) {
      *(float4*)&sa[base]     = make_float4(va[0],va[1],va[2],va[3]);
      *(float4*)&sa[base + 4] = make_float4(va[4],va[5],va[6],va[7]);
      *(float4*)&sb[base]     = make_float4(vb[0],vb[1],vb[2],vb[3]);
      *(float4*)&sb[base + 4] = make_float4(vb[4],vb[5],vb[6],vb[7]);
    }
  }
  if (P > 8) __syncthreads();

  for (int k = 16; k <= P; k <<= 1) {
    // ---- LDS phases: j = k/2 .. 8 (pairs stay within a segment: j < P) ----
    for (int j = k >> 1; j >= 8; j >>= 1) {
      for (int p4 = tid * 4; p4 < (used >> 1); p4 += 1024 * 4) {
        const int i  = ((p4 & ~(j - 1)) << 1) | (p4 & (j - 1)); // 4-aligned
        const int ij = i | j;
        const bool up = ((i & k & (P - 1)) == 0);  // per-segment ascending
        float4 A = *(const float4*)&sa[i];
        float4 B = *(const float4*)&sa[ij];
        float4 lo, hi;
        lo.x = fminf(A.x,B.x); hi.x = fmaxf(A.x,B.x);
        lo.y = fminf(A.y,B.y); hi.y = fmaxf(A.y,B.y);
        lo.z = fminf(A.z,B.z); hi.z = fmaxf(A.z,B.z);
        lo.w = fminf(A.w,B.w); hi.w = fmaxf(A.w,B.w);
        *(float4*)&sa[i]  = sel4(lo, hi, up);
        *(float4*)&sa[ij] = sel4(hi, lo, up);
        float4 C = *(const float4*)&sb[i];
        float4 D = *(const float4*)&sb[ij];
        lo.x = fminf(C.x,D.x); hi.x = fmaxf(C.x,D.x);
        lo.y = fminf(C.y,D.y); hi.y = fmaxf(C.y,D.y);
        lo.z = fminf(C.z,D.z); hi.z = fmaxf(C.z,D.z);
        lo.w = fminf(C.w,D.w); hi.w = fmaxf(C.w,D.w);
        *(float4*)&sb[i]  = sel4(lo, hi, up);
        *(float4*)&sb[ij] = sel4(hi, lo, up);
      }
      __syncthreads();
    }
    // ---- register tail: j = 4,2,1 within own chunk (direction uniform) ----
    const bool last = (k == P);
    if (own) {
      float4 A0 = *(const float4*)&sa[base];
      float4 A1 = *(const float4*)&sa[base + 4];
      va[0]=A0.x; va[1]=A0.y; va[2]=A0.z; va[3]=A0.w;
      va[4]=A1.x; va[5]=A1.y; va[6]=A1.z; va[7]=A1.w;
      float4 B0 = *(const float4*)&sb[base];
      float4 B1 = *(const float4*)&sb[base + 4];
      vb[0]=B0.x; vb[1]=B0.y; vb[2]=B0.z; vb[3]=B0.w;
      vb[4]=B1.x; vb[5]=B1.y; vb[6]=B1.z; vb[7]=B1.w;
      const bool up = ((base & k & (P - 1)) == 0);
      merge8(va, up);
      merge8(vb, up);
      if (!last) {
        *(float4*)&sa[base]     = make_float4(va[0],va[1],va[2],va[3]);
        *(float4*)&sa[base + 4] = make_float4(va[4],va[5],va[6],va[7]);
        *(float4*)&sb[base]     = make_float4(vb[0],vb[1],vb[2],vb[3]);
        *(float4*)&sb[base + 4] = make_float4(vb[4],vb[5],vb[6],vb[7]);
      }
    }
    if (!last) __syncthreads();
  }

  // final sorted chunk lives in registers: accumulate |diff| directly.
  // All F segments share the same m; block adds sum / (m * DIM).
  float s = 0.0f;
  if (own) {
    #pragma unroll
    for (int e = 0; e < 8; ++e)
      if (r + e < m) s += fabsf(va[e] - vb[e]);
  }
  #pragma unroll
  for (int off = 32; off > 0; off >>= 1) s += __shfl_down(s, off);
  if ((tid & 63) == 0) red[tid >> 6] = s;
  __syncthreads();
  if (tid == 0) {
    float tot = 0.0f;
    #pragma unroll
    for (int w = 0; w < 16; ++w) tot += red[w];
    atomicAdd(loss_acc, tot / (float)(m * DIM));
  }
}

__global__ __launch_bounds__(128) void k_final(
    const float* __restrict__ fill_acc, const float* __restrict__ ft,
    const float* __restrict__ loss_acc, float* __restrict__ out)
{
  __shared__ float red[K_CL];
  const int tid = threadIdx.x;
  float v = fill_acc[tid] * (1.0f / (float)N_PTS) - ft[tid];
  red[tid] = v * v;
  __syncthreads();
  for (int s = 64; s > 0; s >>= 1) {
    if (tid < s) red[tid] += red[tid + s];
    __syncthreads();
  }
  if (tid == 0) out[0] = red[0] / (float)K_CL + loss_acc[0];
}

extern "C" void kernel_launch(void* const* d_in, const int* in_sizes, int n_in,
                              void* d_out, int out_size, void* d_ws, size_t ws_size,
                              hipStream_t stream)
{
  (void)in_sizes; (void)n_in; (void)out_size; (void)ws_size;
  const float* x      = (const float*)d_in[0];
  const float* target = (const float*)d_in[1];
  const float* cc     = (const float*)d_in[2];
  const int*   pred_t = (const int*)d_in[3];
  const float* ft     = (const float*)d_in[4];
  float* out = (float*)d_out;

  char* ws = (char*)d_ws;
  float* fill_acc = (float*)(ws + 0);
  float* loss_acc = (float*)(ws + 512);
  int*   pred_x   = (int*)(ws + 1024);
  int*   idx_x    = (int*)(ws + 263168);
  int*   idx_t    = (int*)(ws + 263168 + 4194304);
  int*   count_x  = (int*)(ws + 263168 + 8388608);
  int*   count_t  = (int*)(ws + 263168 + 8388608 + 512);

  k_zero<<<1, 256, 0, stream>>>((float*)ws);
  k_pred_fill<<<N_PTS / 256, 256, 0, stream>>>(x, cc, fill_acc, pred_x);
  k_scatter<<<K_CL * 2, 1024, 0, stream>>>(pred_x, pred_t, idx_x, idx_t,
                                           count_x, count_t);
  k_w1_u<<<K_CL * DIM, 1024, 0, stream>>>(x, target, idx_x, idx_t,
                                          count_x, count_t, loss_acc);
  k_final<<<1, 128, 0, stream>>>(fill_acc, ft, loss_acc, out);
}

// Round 6
// 574.829 us; speedup vs baseline: 2.2408x; 2.2408x over previous
//
#include <hip/hip_runtime.h>
#include <math.h>

#define N_PTS 65536
#define DIM   64
#define K_CL  128
#define EPSV  1e-8f
#define CAP   8192

// ---------------- ws layout (bytes) ----------------
// 0                  : fill_acc[128] float (atomics; zeroed each launch)
// 512                : (unused)
// 1024               : pred_x[N]     int
// 263168             : idx_x[128*CAP] int
// 263168+4194304     : idx_t[128*CAP] int
// 263168+8388608     : count_x[128] int
// +512               : count_t[128] int
// +1024              : parts[8192]  float (one slot per (cluster,feature) task)

__global__ __launch_bounds__(256) void k_zero(float* ws_f) {
  ws_f[threadIdx.x] = 0.0f;  // zeros first 1024 B: fill_acc
}

// one thread per point; centers read via wave-uniform (scalarized) global
// loads -> s_load through scalar cache, VALU does pure v_fmac.
__global__ __launch_bounds__(256) void k_pred_fill(
    const float* __restrict__ x, const float* __restrict__ centers,
    float* __restrict__ fill_acc, int* __restrict__ pred_x)
{
  __shared__ float csq[K_CL];
  __shared__ float fill_lds[K_CL];
  const int tid = threadIdx.x;

  if (tid < K_CL) {
    const float* cp = centers + tid * DIM;
    float s = 0.0f;
    #pragma unroll 8
    for (int d = 0; d < DIM; ++d) { float v = cp[d]; s += v * v; }
    csq[tid] = s;
    fill_lds[tid] = 0.0f;
  }

  const int i = blockIdx.x * 256 + tid;
  float xr[DIM];
  const float4* xp = reinterpret_cast<const float4*>(x + (size_t)i * DIM);
  #pragma unroll
  for (int q = 0; q < DIM / 4; ++q) {
    float4 v = xp[q];
    xr[4 * q + 0] = v.x; xr[4 * q + 1] = v.y;
    xr[4 * q + 2] = v.z; xr[4 * q + 3] = v.w;
  }
  float xsq = 0.0f;
  #pragma unroll
  for (int d = 0; d < DIM; ++d) xsq += xr[d] * xr[d];
  __syncthreads();

  // ---- pass 1: sumw + argmin (first-index tie-break via strict <) ----
  float sumw = 0.0f;
  float best = INFINITY;
  int   bestj = 0;
  #pragma unroll 2
  for (int j = 0; j < K_CL; ++j) {
    const float* cp = centers + j * DIM;   // uniform address -> s_load
    float d0 = 0.f, d1 = 0.f, d2a = 0.f, d3 = 0.f;
    #pragma unroll
    for (int d = 0; d < DIM; d += 4) {
      d0  += xr[d + 0] * cp[d + 0];
      d1  += xr[d + 1] * cp[d + 1];
      d2a += xr[d + 2] * cp[d + 2];
      d3  += xr[d + 3] * cp[d + 3];
    }
    float dot  = (d0 + d1) + (d2a + d3);
    float dsq  = xsq + csq[j] - 2.0f * dot;
    float dist = sqrtf(fmaxf(dsq, 0.0f));
    float w    = 1.0f / (dist + EPSV);
    sumw += w;
    if (dist < best) { best = dist; bestj = j; }
  }
  pred_x[i] = bestj;
  const float inv = 1.0f / sumw;
  const int lane = tid & 63;

  // ---- pass 2: normalized weights -> per-cluster sums ----
  #pragma unroll 2
  for (int j = 0; j < K_CL; ++j) {
    const float* cp = centers + j * DIM;   // uniform address -> s_load
    float d0 = 0.f, d1 = 0.f, d2a = 0.f, d3 = 0.f;
    #pragma unroll
    for (int d = 0; d < DIM; d += 4) {
      d0  += xr[d + 0] * cp[d + 0];
      d1  += xr[d + 1] * cp[d + 1];
      d2a += xr[d + 2] * cp[d + 2];
      d3  += xr[d + 3] * cp[d + 3];
    }
    float dot  = (d0 + d1) + (d2a + d3);
    float dsq  = xsq + csq[j] - 2.0f * dot;
    float dist = sqrtf(fmaxf(dsq, 0.0f));
    float wn   = (1.0f / (dist + EPSV)) * inv;
    #pragma unroll
    for (int off = 32; off > 0; off >>= 1) wn += __shfl_down(wn, off);
    if (lane == 0) atomicAdd(&fill_lds[j], wn);
  }
  __syncthreads();
  if (tid < K_CL) atomicAdd(&fill_acc[tid], fill_lds[tid]);
}

// stable (index-ordered) member-list build: one block per (cluster, side)
__global__ __launch_bounds__(1024) void k_scatter(
    const int* __restrict__ pred_x, const int* __restrict__ pred_t,
    int* __restrict__ idx_x, int* __restrict__ idx_t,
    int* __restrict__ count_x, int* __restrict__ count_t)
{
  const int c    = blockIdx.x >> 1;
  const int side = blockIdx.x & 1;
  const int* __restrict__ pred = side ? pred_t : pred_x;
  int* __restrict__ out = side ? idx_t : idx_x;
  int* __restrict__ cnt = side ? count_t : count_x;

  __shared__ int wsum[16];
  const int tid = threadIdx.x, lane = tid & 63, w = tid >> 6;
  int base = 0;
  for (int start = 0; start < N_PTS; start += 1024) {
    const int i = start + tid;                 // N % 1024 == 0
    const bool m = (pred[i] == c);
    unsigned long long bal = __ballot(m);
    int lp = __popcll(bal & ((1ull << lane) - 1ull));
    if (lane == 0) wsum[w] = __popcll(bal);
    __syncthreads();
    int wbase = 0, tot = 0;
    #pragma unroll
    for (int k = 0; k < 16; ++k) { int v = wsum[k]; tot += v; if (k < w) wbase += v; }
    if (m) { int pos = base + wbase + lp; if (pos < CAP) out[c * CAP + pos] = i; }
    base += tot;
    __syncthreads();
  }
  if (tid == 0) cnt[c] = base;
}

// ---- in-register bitonic helpers (8 contiguous elements / thread) ----
__device__ __forceinline__ void ce(float& a, float& b, bool up) {
  float lo = fminf(a, b), hi = fmaxf(a, b);
  a = up ? lo : hi;
  b = up ? hi : lo;
}

__device__ __forceinline__ void merge8(float v[8], bool up) {
  ce(v[0],v[4],up); ce(v[1],v[5],up); ce(v[2],v[6],up); ce(v[3],v[7],up);
  ce(v[0],v[2],up); ce(v[1],v[3],up); ce(v[4],v[6],up); ce(v[5],v[7],up);
  ce(v[0],v[1],up); ce(v[2],v[3],up); ce(v[4],v[5],up); ce(v[6],v[7],up);
}

__device__ __forceinline__ void sort8(float v[8], bool up8) {
  ce(v[0],v[1],true );  ce(v[2],v[3],false); ce(v[4],v[5],true );  ce(v[6],v[7],false);
  ce(v[0],v[2],true );  ce(v[1],v[3],true );  ce(v[4],v[6],false); ce(v[5],v[7],false);
  ce(v[0],v[1],true );  ce(v[2],v[3],true );  ce(v[4],v[5],false); ce(v[6],v[7],false);
  merge8(v, up8);
}

// lane-exchange phases j = min(k/2,256)..8 via shfl_xor (no LDS, no barrier),
// then register phases j=4,2,1. ib = element base index of this thread's
// chunk; up/low masks derived from ib. Works inside one 512-element
// wave-chunk (i & 511 addressing is implicit: jl <= 32 stays in-wave).
__device__ __forceinline__ void stage_tail(float va[8], float vb[8],
                                           int ib, int k, bool up) {
  for (int j = (k >> 1) > 256 ? 256 : (k >> 1); j >= 8; j >>= 1) {
    const int  jl = j >> 3;
    const bool low = ((ib & j) == 0);
    const bool tm  = (up == low);
    #pragma unroll
    for (int e = 0; e < 8; ++e) {
      float p = __shfl_xor(va[e], jl, 64);
      va[e] = tm ? fminf(va[e], p) : fmaxf(va[e], p);
      float q = __shfl_xor(vb[e], jl, 64);
      vb[e] = tm ? fminf(vb[e], q) : fmaxf(vb[e], q);
    }
  }
  merge8(va, up);
  merge8(vb, up);
}

// Small class: one wave per (cluster, feature) task, m <= 512. Pads to a
// fixed 512-sort in registers+shuffles. No LDS arena, no __syncthreads.
// Writes parts[task]; writes 0 for m==0; leaves m>512 slots to mid/big.
__global__ __launch_bounds__(256) void k_w1_wave(
    const float* __restrict__ x, const float* __restrict__ t,
    const int* __restrict__ idx_x, const int* __restrict__ idx_t,
    const int* __restrict__ count_x, const int* __restrict__ count_t,
    float* __restrict__ parts)
{
  const int task = blockIdx.x * 4 + (threadIdx.x >> 6);
  const int lane = threadIdx.x & 63;
  const int c = task >> 6, d = task & 63;
  const int m = min(min(count_x[c], CAP), min(count_t[c], CAP));
  if (m > 512) return;                       // mid/big class writes this slot
  if (m == 0) { if (lane == 0) parts[task] = 0.0f; return; }

  const int ib = lane << 3;                  // element base in [0,512)
  const int gb = c * CAP + ib;
  float va[8], vb[8];
  #pragma unroll
  for (int e = 0; e < 8; ++e) {
    if (ib + e < m) {
      va[e] = x[(size_t)idx_x[gb + e] * DIM + d];
      vb[e] = t[(size_t)idx_t[gb + e] * DIM + d];
    } else { va[e] = INFINITY; vb[e] = INFINITY; }
  }

  const bool u8 = ((ib & 8) == 0);
  sort8(va, u8);
  sort8(vb, u8);
  for (int k = 16; k <= 512; k <<= 1) {
    const bool up = ((ib & k) == 0);         // k=512 -> true: final ascending
    stage_tail(va, vb, ib, k, up);
  }

  float s = 0.0f;
  #pragma unroll
  for (int e = 0; e < 8; ++e)
    if (ib + e < m) s += fabsf(va[e] - vb[e]);
  #pragma unroll
  for (int off = 32; off > 0; off >>= 1) s += __shfl_down(s, off);
  if (lane == 0) parts[task] = s / (float)(m * DIM);
}

// Mid/big classes: one block per task, PTOT-element padded sort
// (PTOT = BDIM*8). LDS only for phases j >= 512 (cross-wave); everything
// else in registers+shuffles. MLO < m <= MHI selects the class.
template<int PTOT, int BDIM, int MLO, int MHI>
__global__ __launch_bounds__(BDIM) void k_w1_ldst(
    const float* __restrict__ x, const float* __restrict__ t,
    const int* __restrict__ idx_x, const int* __restrict__ idx_t,
    const int* __restrict__ count_x, const int* __restrict__ count_t,
    float* __restrict__ parts)
{
  __shared__ float sa[PTOT];
  __shared__ float sb[PTOT];
  __shared__ float red[BDIM / 64];
  const int task = blockIdx.x;
  const int c = task >> 6, d = task & 63;
  const int m = min(min(count_x[c], CAP), min(count_t[c], CAP));
  if (m <= MLO || m > MHI) return;

  const int tid = threadIdx.x;
  const int ib  = tid << 3;                  // element base in [0,PTOT)
  const int gb  = c * CAP + ib;
  float va[8], vb[8];
  #pragma unroll
  for (int e = 0; e < 8; ++e) {
    if (ib + e < m) {
      va[e] = x[(size_t)idx_x[gb + e] * DIM + d];
      vb[e] = t[(size_t)idx_t[gb + e] * DIM + d];
    } else { va[e] = INFINITY; vb[e] = INFINITY; }
  }

  const bool u8 = ((ib & 8) == 0);
  sort8(va, u8);
  sort8(vb, u8);
  for (int k = 16; k <= PTOT; k <<= 1) {
    const bool up = ((ib & k) == 0);
    // LDS phases: j = k/2 .. 512 (cross-wave exchanges)
    for (int j = k >> 1; j >= 512; j >>= 1) {
      __syncthreads();                       // WAR: prior partner reads done
      *(float4*)&sa[ib]     = make_float4(va[0],va[1],va[2],va[3]);
      *(float4*)&sa[ib + 4] = make_float4(va[4],va[5],va[6],va[7]);
      *(float4*)&sb[ib]     = make_float4(vb[0],vb[1],vb[2],vb[3]);
      *(float4*)&sb[ib + 4] = make_float4(vb[4],vb[5],vb[6],vb[7]);
      __syncthreads();
      const int pi = ib ^ j;
      float4 A0 = *(const float4*)&sa[pi];
      float4 A1 = *(const float4*)&sa[pi + 4];
      float4 B0 = *(const float4*)&sb[pi];
      float4 B1 = *(const float4*)&sb[pi + 4];
      const bool low = ((ib & j) == 0);
      const bool tm  = (up == low);
      float pa[8] = {A0.x,A0.y,A0.z,A0.w,A1.x,A1.y,A1.z,A1.w};
      float pb[8] = {B0.x,B0.y,B0.z,B0.w,B1.x,B1.y,B1.z,B1.w};
      #pragma unroll
      for (int e = 0; e < 8; ++e) {
        va[e] = tm ? fminf(va[e], pa[e]) : fmaxf(va[e], pa[e]);
        vb[e] = tm ? fminf(vb[e], pb[e]) : fmaxf(vb[e], pb[e]);
      }
    }
    // in-wave phases j <= 256 + register tail
    stage_tail(va, vb, ib, k, up);
  }

  float s = 0.0f;
  #pragma unroll
  for (int e = 0; e < 8; ++e)
    if (ib + e < m) s += fabsf(va[e] - vb[e]);
  #pragma unroll
  for (int off = 32; off > 0; off >>= 1) s += __shfl_down(s, off);
  __syncthreads();
  if ((tid & 63) == 0) red[tid >> 6] = s;
  __syncthreads();
  if (tid == 0) {
    float tot = 0.0f;
    #pragma unroll
    for (int w = 0; w < BDIM / 64; ++w) tot += red[w];
    parts[task] = tot / (float)(m * DIM);
  }
}

__global__ __launch_bounds__(1024) void k_final(
    const float* __restrict__ fill_acc, const float* __restrict__ ft,
    const float* __restrict__ parts, float* __restrict__ out)
{
  __shared__ float red[16];
  const int tid = threadIdx.x;
  float s = 0.0f;
  #pragma unroll
  for (int i = 0; i < 8; ++i) s += parts[tid + i * 1024];
  if (tid < K_CL) {
    float v = fill_acc[tid] * (1.0f / (float)N_PTS) - ft[tid];
    s += v * v * (1.0f / (float)K_CL);
  }
  #pragma unroll
  for (int off = 32; off > 0; off >>= 1) s += __shfl_down(s, off);
  if ((tid & 63) == 0) red[tid >> 6] = s;
  __syncthreads();
  if (tid == 0) {
    float tot = 0.0f;
    #pragma unroll
    for (int w = 0; w < 16; ++w) tot += red[w];
    out[0] = tot;
  }
}

extern "C" void kernel_launch(void* const* d_in, const int* in_sizes, int n_in,
                              void* d_out, int out_size, void* d_ws, size_t ws_size,
                              hipStream_t stream)
{
  (void)in_sizes; (void)n_in; (void)out_size; (void)ws_size;
  const float* x      = (const float*)d_in[0];
  const float* target = (const float*)d_in[1];
  const float* cc     = (const float*)d_in[2];
  const int*   pred_t = (const int*)d_in[3];
  const float* ft     = (const float*)d_in[4];
  float* out = (float*)d_out;

  char* ws = (char*)d_ws;
  float* fill_acc = (float*)(ws + 0);
  int*   pred_x   = (int*)(ws + 1024);
  int*   idx_x    = (int*)(ws + 263168);
  int*   idx_t    = (int*)(ws + 263168 + 4194304);
  int*   count_x  = (int*)(ws + 263168 + 8388608);
  int*   count_t  = (int*)(ws + 263168 + 8388608 + 512);
  float* parts    = (float*)(ws + 263168 + 8388608 + 1024);

  k_zero<<<1, 256, 0, stream>>>((float*)ws);
  k_pred_fill<<<N_PTS / 256, 256, 0, stream>>>(x, cc, fill_acc, pred_x);
  k_scatter<<<K_CL * 2, 1024, 0, stream>>>(pred_x, pred_t, idx_x, idx_t,
                                           count_x, count_t);
  // W1 classes (disjoint by m): wave (m<=512, no LDS/barriers),
  // mid (512<m<=2048, 16 KB LDS, 3 LDS phases), big (m>2048, 64 KB, <=10).
  k_w1_wave<<<K_CL * DIM / 4, 256, 0, stream>>>(
      x, target, idx_x, idx_t, count_x, count_t, parts);
  k_w1_ldst<2048, 256, 512, 2048><<<K_CL * DIM, 256, 0, stream>>>(
      x, target, idx_x, idx_t, count_x, count_t, parts);
  k_w1_ldst<8192, 1024, 2048, 8192><<<K_CL * DIM, 1024, 0, stream>>>(
      x, target, idx_x, idx_t, count_x, count_t, parts);
  k_final<<<1, 1024, 0, stream>>>(fill_acc, ft, parts, out);
}

// Round 7
// 533.219 us; speedup vs baseline: 2.4157x; 1.0780x over previous
//
#include <hip/hip_runtime.h>
#include <math.h>

#define N_PTS 65536
#define DIM   64
#define K_CL  128
#define EPSV  1e-8f
#define CAP   8192

// ---------------- ws layout (bytes) ----------------
// 0                  : fill_acc[128] float (atomics; zeroed each launch)
// 1024               : pred_x[N]     int
// 263168             : idx_x[128*CAP] int
// 263168+4194304     : idx_t[128*CAP] int
// 263168+8388608     : count_x[128] int
// +512               : count_t[128] int
// +1024              : parts[8192]  float (one slot per (cluster,feature) task)

__global__ __launch_bounds__(256) void k_zero(float* ws_f) {
  ws_f[threadIdx.x] = 0.0f;  // zeros first 1024 B: fill_acc
}

// one thread per point; centers read via wave-uniform (scalarized) global
// loads -> s_load through scalar cache, VALU does pure v_fmac.
__global__ __launch_bounds__(256) void k_pred_fill(
    const float* __restrict__ x, const float* __restrict__ centers,
    float* __restrict__ fill_acc, int* __restrict__ pred_x)
{
  __shared__ float csq[K_CL];
  __shared__ float fill_lds[K_CL];
  const int tid = threadIdx.x;

  if (tid < K_CL) {
    const float* cp = centers + tid * DIM;
    float s = 0.0f;
    #pragma unroll 8
    for (int d = 0; d < DIM; ++d) { float v = cp[d]; s += v * v; }
    csq[tid] = s;
    fill_lds[tid] = 0.0f;
  }

  const int i = blockIdx.x * 256 + tid;
  float xr[DIM];
  const float4* xp = reinterpret_cast<const float4*>(x + (size_t)i * DIM);
  #pragma unroll
  for (int q = 0; q < DIM / 4; ++q) {
    float4 v = xp[q];
    xr[4 * q + 0] = v.x; xr[4 * q + 1] = v.y;
    xr[4 * q + 2] = v.z; xr[4 * q + 3] = v.w;
  }
  float xsq = 0.0f;
  #pragma unroll
  for (int d = 0; d < DIM; ++d) xsq += xr[d] * xr[d];
  __syncthreads();

  // ---- pass 1: sumw + argmin (first-index tie-break via strict <) ----
  float sumw = 0.0f;
  float best = INFINITY;
  int   bestj = 0;
  #pragma unroll 2
  for (int j = 0; j < K_CL; ++j) {
    const float* cp = centers + j * DIM;   // uniform address -> s_load
    float d0 = 0.f, d1 = 0.f, d2a = 0.f, d3 = 0.f;
    #pragma unroll
    for (int d = 0; d < DIM; d += 4) {
      d0  += xr[d + 0] * cp[d + 0];
      d1  += xr[d + 1] * cp[d + 1];
      d2a += xr[d + 2] * cp[d + 2];
      d3  += xr[d + 3] * cp[d + 3];
    }
    float dot  = (d0 + d1) + (d2a + d3);
    float dsq  = xsq + csq[j] - 2.0f * dot;
    float dist = sqrtf(fmaxf(dsq, 0.0f));
    float w    = 1.0f / (dist + EPSV);
    sumw += w;
    if (dist < best) { best = dist; bestj = j; }
  }
  pred_x[i] = bestj;
  const float inv = 1.0f / sumw;
  const int lane = tid & 63;

  // ---- pass 2: normalized weights -> per-cluster sums ----
  #pragma unroll 2
  for (int j = 0; j < K_CL; ++j) {
    const float* cp = centers + j * DIM;   // uniform address -> s_load
    float d0 = 0.f, d1 = 0.f, d2a = 0.f, d3 = 0.f;
    #pragma unroll
    for (int d = 0; d < DIM; d += 4) {
      d0  += xr[d + 0] * cp[d + 0];
      d1  += xr[d + 1] * cp[d + 1];
      d2a += xr[d + 2] * cp[d + 2];
      d3  += xr[d + 3] * cp[d + 3];
    }
    float dot  = (d0 + d1) + (d2a + d3);
    float dsq  = xsq + csq[j] - 2.0f * dot;
    float dist = sqrtf(fmaxf(dsq, 0.0f));
    float wn   = (1.0f / (dist + EPSV)) * inv;
    #pragma unroll
    for (int off = 32; off > 0; off >>= 1) wn += __shfl_down(wn, off);
    if (lane == 0) atomicAdd(&fill_lds[j], wn);
  }
  __syncthreads();
  if (tid < K_CL) atomicAdd(&fill_acc[tid], fill_lds[tid]);
}

// stable (index-ordered) member-list build: one block per (cluster, side)
__global__ __launch_bounds__(1024) void k_scatter(
    const int* __restrict__ pred_x, const int* __restrict__ pred_t,
    int* __restrict__ idx_x, int* __restrict__ idx_t,
    int* __restrict__ count_x, int* __restrict__ count_t)
{
  const int c    = blockIdx.x >> 1;
  const int side = blockIdx.x & 1;
  const int* __restrict__ pred = side ? pred_t : pred_x;
  int* __restrict__ out = side ? idx_t : idx_x;
  int* __restrict__ cnt = side ? count_t : count_x;

  __shared__ int wsum[16];
  const int tid = threadIdx.x, lane = tid & 63, w = tid >> 6;
  int base = 0;
  for (int start = 0; start < N_PTS; start += 1024) {
    const int i = start + tid;                 // N % 1024 == 0
    const bool m = (pred[i] == c);
    unsigned long long bal = __ballot(m);
    int lp = __popcll(bal & ((1ull << lane) - 1ull));
    if (lane == 0) wsum[w] = __popcll(bal);
    __syncthreads();
    int wbase = 0, tot = 0;
    #pragma unroll
    for (int k = 0; k < 16; ++k) { int v = wsum[k]; tot += v; if (k < w) wbase += v; }
    if (m) { int pos = base + wbase + lp; if (pos < CAP) out[c * CAP + pos] = i; }
    base += tot;
    __syncthreads();
  }
  if (tid == 0) cnt[c] = base;
}

// ---- in-register bitonic helpers ----
__device__ __forceinline__ void ce(float& a, float& b, bool up) {
  float lo = fminf(a, b), hi = fmaxf(a, b);
  a = up ? lo : hi;
  b = up ? hi : lo;
}

__device__ __forceinline__ void merge8(float* v, bool up) {
  ce(v[0],v[4],up); ce(v[1],v[5],up); ce(v[2],v[6],up); ce(v[3],v[7],up);
  ce(v[0],v[2],up); ce(v[1],v[3],up); ce(v[4],v[6],up); ce(v[5],v[7],up);
  ce(v[0],v[1],up); ce(v[2],v[3],up); ce(v[4],v[5],up); ce(v[6],v[7],up);
}

__device__ __forceinline__ void sort8(float* v, bool up8) {
  ce(v[0],v[1],true );  ce(v[2],v[3],false); ce(v[4],v[5],true );  ce(v[6],v[7],false);
  ce(v[0],v[2],true );  ce(v[1],v[3],true );  ce(v[4],v[6],false); ce(v[5],v[7],false);
  ce(v[0],v[1],true );  ce(v[2],v[3],true );  ce(v[4],v[5],false); ce(v[6],v[7],false);
  merge8(v, up8);
}

__device__ __forceinline__ void merge16(float* v, bool up) {
  #pragma unroll
  for (int e = 0; e < 8; ++e) ce(v[e], v[e + 8], up);
  merge8(v, up);
  merge8(v + 8, up);
}

__device__ __forceinline__ void sort16(float* v, bool up16) {
  sort8(v, true);
  sort8(v + 8, false);
  merge16(v, up16);
}

// V=8: shuffle phases j=min(k/2,256)..8, then register j=4,2,1
__device__ __forceinline__ void stage_tail(float va[8], float vb[8],
                                           int ib, int k, bool up) {
  for (int j = (k >> 1) > 256 ? 256 : (k >> 1); j >= 8; j >>= 1) {
    const int  jl = j >> 3;
    const bool low = ((ib & j) == 0);
    const bool tm  = (up == low);
    #pragma unroll
    for (int e = 0; e < 8; ++e) {
      float p = __shfl_xor(va[e], jl, 64);
      va[e] = tm ? fminf(va[e], p) : fmaxf(va[e], p);
      float q = __shfl_xor(vb[e], jl, 64);
      vb[e] = tm ? fminf(vb[e], q) : fmaxf(vb[e], q);
    }
  }
  merge8(va, up);
  merge8(vb, up);
}

// V=16: shuffle phases j=min(k/2,512)..16, then register j=8..1 (merge16)
__device__ __forceinline__ void stage_tail16(float va[16], float vb[16],
                                             int ib, int k, bool up) {
  for (int j = (k >> 1) > 512 ? 512 : (k >> 1); j >= 16; j >>= 1) {
    const int  jl = j >> 4;
    const bool low = ((ib & j) == 0);
    const bool tm  = (up == low);
    #pragma unroll
    for (int e = 0; e < 16; ++e) {
      float p = __shfl_xor(va[e], jl, 64);
      va[e] = tm ? fminf(va[e], p) : fmaxf(va[e], p);
      float q = __shfl_xor(vb[e], jl, 64);
      vb[e] = tm ? fminf(vb[e], q) : fmaxf(vb[e], q);
    }
  }
  merge16(va, up);
  merge16(vb, up);
}

// Wave class: one wave per (cluster, feature) task, m <= 1024. No LDS, no
// barriers. m<=512: V=8 with adaptive P; 512<m<=1024: V=16, P=1024.
__global__ __launch_bounds__(256, 4) void k_w1_wave(
    const float* __restrict__ x, const float* __restrict__ t,
    const int* __restrict__ idx_x, const int* __restrict__ idx_t,
    const int* __restrict__ count_x, const int* __restrict__ count_t,
    float* __restrict__ parts)
{
  const int task = blockIdx.x * 4 + (threadIdx.x >> 6);
  const int lane = threadIdx.x & 63;
  const int c = task >> 6, d = task & 63;
  const int m = min(min(count_x[c], CAP), min(count_t[c], CAP));
  if (m > 1024) return;                      // mid/big class writes this slot
  if (m == 0) { if (lane == 0) parts[task] = 0.0f; return; }

  float s = 0.0f;
  if (m <= 512) {
    int P = 8;
    while (P < m) P <<= 1;
    const int ib = lane << 3;
    const int gb = c * CAP + ib;
    float va[8], vb[8];
    #pragma unroll
    for (int e = 0; e < 8; ++e) {
      if (ib + e < m) {
        va[e] = x[(size_t)idx_x[gb + e] * DIM + d];
        vb[e] = t[(size_t)idx_t[gb + e] * DIM + d];
      } else { va[e] = INFINITY; vb[e] = INFINITY; }
    }
    const bool u8 = ((ib & 8) == 0);
    sort8(va, u8);
    sort8(vb, u8);
    for (int k = 16; k <= P; k <<= 1)
      stage_tail(va, vb, ib, k, ((ib & k) == 0));
    #pragma unroll
    for (int e = 0; e < 8; ++e)
      if (ib + e < m) s += fabsf(va[e] - vb[e]);
  } else {
    const int ib = lane << 4;               // P = 1024, all lanes active
    const int gb = c * CAP + ib;
    float va[16], vb[16];
    #pragma unroll
    for (int e = 0; e < 16; ++e) {
      if (ib + e < m) {
        va[e] = x[(size_t)idx_x[gb + e] * DIM + d];
        vb[e] = t[(size_t)idx_t[gb + e] * DIM + d];
      } else { va[e] = INFINITY; vb[e] = INFINITY; }
    }
    const bool u16 = ((ib & 16) == 0);
    sort16(va, u16);
    sort16(vb, u16);
    for (int k = 32; k <= 1024; k <<= 1)
      stage_tail16(va, vb, ib, k, ((ib & k) == 0));
    #pragma unroll
    for (int e = 0; e < 16; ++e)
      if (ib + e < m) s += fabsf(va[e] - vb[e]);
  }
  #pragma unroll
  for (int off = 32; off > 0; off >>= 1) s += __shfl_down(s, off);
  if (lane == 0) parts[task] = s / (float)(m * DIM);
}

// Mid class: 1024 < m <= 2048. BDIM=128, V=16, P=2048. Exactly one LDS
// phase (j=1024 in the k=2048 stage); everything else registers+shuffles.
__global__ __launch_bounds__(128, 4) void k_w1_mid(
    const float* __restrict__ x, const float* __restrict__ t,
    const int* __restrict__ idx_x, const int* __restrict__ idx_t,
    const int* __restrict__ count_x, const int* __restrict__ count_t,
    float* __restrict__ parts)
{
  __shared__ float sa[2048];   // 8 KB
  __shared__ float sb[2048];   // 8 KB
  __shared__ float red[2];
  const int task = blockIdx.x;
  const int c = task >> 6, d = task & 63;
  const int m = min(min(count_x[c], CAP), min(count_t[c], CAP));
  if (m <= 1024 || m > 2048) return;

  const int tid = threadIdx.x;
  const int ib  = tid << 4;
  const int gb  = c * CAP + ib;
  float va[16], vb[16];
  #pragma unroll
  for (int e = 0; e < 16; ++e) {
    if (ib + e < m) {
      va[e] = x[(size_t)idx_x[gb + e] * DIM + d];
      vb[e] = t[(size_t)idx_t[gb + e] * DIM + d];
    } else { va[e] = INFINITY; vb[e] = INFINITY; }
  }
  const bool u16 = ((ib & 16) == 0);
  sort16(va, u16);
  sort16(vb, u16);
  for (int k = 32; k <= 1024; k <<= 1)
    stage_tail16(va, vb, ib, k, ((ib & k) == 0));

  // k = 2048 stage: LDS phase j = 1024
  #pragma unroll
  for (int q = 0; q < 4; ++q) {
    *(float4*)&sa[ib + 4 * q] = make_float4(va[4*q],va[4*q+1],va[4*q+2],va[4*q+3]);
    *(float4*)&sb[ib + 4 * q] = make_float4(vb[4*q],vb[4*q+1],vb[4*q+2],vb[4*q+3]);
  }
  __syncthreads();
  {
    const int pi = ib ^ 1024;
    const bool tm = ((ib & 1024) == 0);   // up(k=2048)=true; tm = low
    #pragma unroll
    for (int q = 0; q < 4; ++q) {
      float4 A = *(const float4*)&sa[pi + 4 * q];
      float4 B = *(const float4*)&sb[pi + 4 * q];
      va[4*q+0] = tm ? fminf(va[4*q+0],A.x) : fmaxf(va[4*q+0],A.x);
      va[4*q+1] = tm ? fminf(va[4*q+1],A.y) : fmaxf(va[4*q+1],A.y);
      va[4*q+2] = tm ? fminf(va[4*q+2],A.z) : fmaxf(va[4*q+2],A.z);
      va[4*q+3] = tm ? fminf(va[4*q+3],A.w) : fmaxf(va[4*q+3],A.w);
      vb[4*q+0] = tm ? fminf(vb[4*q+0],B.x) : fmaxf(vb[4*q+0],B.x);
      vb[4*q+1] = tm ? fminf(vb[4*q+1],B.y) : fmaxf(vb[4*q+1],B.y);
      vb[4*q+2] = tm ? fminf(vb[4*q+2],B.z) : fmaxf(vb[4*q+2],B.z);
      vb[4*q+3] = tm ? fminf(vb[4*q+3],B.w) : fmaxf(vb[4*q+3],B.w);
    }
  }
  stage_tail16(va, vb, ib, 2048, true);

  float s = 0.0f;
  #pragma unroll
  for (int e = 0; e < 16; ++e)
    if (ib + e < m) s += fabsf(va[e] - vb[e]);
  #pragma unroll
  for (int off = 32; off > 0; off >>= 1) s += __shfl_down(s, off);
  if ((tid & 63) == 0) red[tid >> 6] = s;
  __syncthreads();
  if (tid == 0) parts[task] = (red[0] + red[1]) / (float)(m * DIM);
}

// Big class: m > 2048. BDIM=512, V=16, adaptive P in {4096, 8192}. LDS only
// for j >= 1024 (P=4096: 3 phases / 6 barriers; P=8192: 6 / 12).
__global__ __launch_bounds__(512, 4) void k_w1_big(
    const float* __restrict__ x, const float* __restrict__ t,
    const int* __restrict__ idx_x, const int* __restrict__ idx_t,
    const int* __restrict__ count_x, const int* __restrict__ count_t,
    float* __restrict__ parts)
{
  __shared__ float sa[8192];   // 32 KB
  __shared__ float sb[8192];   // 32 KB
  __shared__ float red[8];
  const int task = blockIdx.x;
  const int c = task >> 6, d = task & 63;
  const int m = min(min(count_x[c], CAP), min(count_t[c], CAP));
  if (m <= 2048) return;
  const int P = (m > 4096) ? 8192 : 4096;

  const int tid = threadIdx.x;
  const int ib  = tid << 4;
  const bool active = (ib < P);
  const int gb  = c * CAP + ib;
  float va[16], vb[16];
  if (active) {
    #pragma unroll
    for (int e = 0; e < 16; ++e) {
      if (ib + e < m) {
        va[e] = x[(size_t)idx_x[gb + e] * DIM + d];
        vb[e] = t[(size_t)idx_t[gb + e] * DIM + d];
      } else { va[e] = INFINITY; vb[e] = INFINITY; }
    }
    const bool u16 = ((ib & 16) == 0);
    sort16(va, u16);
    sort16(vb, u16);
  }

  for (int k = 32; k <= P; k <<= 1) {
    const bool up = ((ib & k) == 0);
    for (int j = k >> 1; j >= 1024; j >>= 1) {
      __syncthreads();                       // WAR vs prior phase's reads
      if (active) {
        #pragma unroll
        for (int q = 0; q < 4; ++q) {
          *(float4*)&sa[ib + 4*q] = make_float4(va[4*q],va[4*q+1],va[4*q+2],va[4*q+3]);
          *(float4*)&sb[ib + 4*q] = make_float4(vb[4*q],vb[4*q+1],vb[4*q+2],vb[4*q+3]);
        }
      }
      __syncthreads();
      if (active) {
        const int pi = ib ^ j;
        const bool tm = (up == ((ib & j) == 0));
        #pragma unroll
        for (int q = 0; q < 4; ++q) {
          float4 A = *(const float4*)&sa[pi + 4*q];
          float4 B = *(const float4*)&sb[pi + 4*q];
          va[4*q+0] = tm ? fminf(va[4*q+0],A.x) : fmaxf(va[4*q+0],A.x);
          va[4*q+1] = tm ? fminf(va[4*q+1],A.y) : fmaxf(va[4*q+1],A.y);
          va[4*q+2] = tm ? fminf(va[4*q+2],A.z) : fmaxf(va[4*q+2],A.z);
          va[4*q+3] = tm ? fminf(va[4*q+3],A.w) : fmaxf(va[4*q+3],A.w);
          vb[4*q+0] = tm ? fminf(vb[4*q+0],B.x) : fmaxf(vb[4*q+0],B.x);
          vb[4*q+1] = tm ? fminf(vb[4*q+1],B.y) : fmaxf(vb[4*q+1],B.y);
          vb[4*q+2] = tm ? fminf(vb[4*q+2],B.z) : fmaxf(vb[4*q+2],B.z);
          vb[4*q+3] = tm ? fminf(vb[4*q+3],B.w) : fmaxf(vb[4*q+3],B.w);
        }
      }
    }
    if (active) stage_tail16(va, vb, ib, k, up);
  }

  float s = 0.0f;
  if (active) {
    #pragma unroll
    for (int e = 0; e < 16; ++e)
      if (ib + e < m) s += fabsf(va[e] - vb[e]);
  }
  #pragma unroll
  for (int off = 32; off > 0; off >>= 1) s += __shfl_down(s, off);
  __syncthreads();
  if ((tid & 63) == 0) red[tid >> 6] = s;
  __syncthreads();
  if (tid == 0) {
    float tot = 0.0f;
    #pragma unroll
    for (int w = 0; w < 8; ++w) tot += red[w];
    parts[task] = tot / (float)(m * DIM);
  }
}

__global__ __launch_bounds__(1024) void k_final(
    const float* __restrict__ fill_acc, const float* __restrict__ ft,
    const float* __restrict__ parts, float* __restrict__ out)
{
  __shared__ float red[16];
  const int tid = threadIdx.x;
  float s = 0.0f;
  #pragma unroll
  for (int i = 0; i < 8; ++i) s += parts[tid + i * 1024];
  if (tid < K_CL) {
    float v = fill_acc[tid] * (1.0f / (float)N_PTS) - ft[tid];
    s += v * v * (1.0f / (float)K_CL);
  }
  #pragma unroll
  for (int off = 32; off > 0; off >>= 1) s += __shfl_down(s, off);
  if ((tid & 63) == 0) red[tid >> 6] = s;
  __syncthreads();
  if (tid == 0) {
    float tot = 0.0f;
    #pragma unroll
    for (int w = 0; w < 16; ++w) tot += red[w];
    out[0] = tot;
  }
}

extern "C" void kernel_launch(void* const* d_in, const int* in_sizes, int n_in,
                              void* d_out, int out_size, void* d_ws, size_t ws_size,
                              hipStream_t stream)
{
  (void)in_sizes; (void)n_in; (void)out_size; (void)ws_size;
  const float* x      = (const float*)d_in[0];
  const float* target = (const float*)d_in[1];
  const float* cc     = (const float*)d_in[2];
  const int*   pred_t = (const int*)d_in[3];
  const float* ft     = (const float*)d_in[4];
  float* out = (float*)d_out;

  char* ws = (char*)d_ws;
  float* fill_acc = (float*)(ws + 0);
  int*   pred_x   = (int*)(ws + 1024);
  int*   idx_x    = (int*)(ws + 263168);
  int*   idx_t    = (int*)(ws + 263168 + 4194304);
  int*   count_x  = (int*)(ws + 263168 + 8388608);
  int*   count_t  = (int*)(ws + 263168 + 8388608 + 512);
  float* parts    = (float*)(ws + 263168 + 8388608 + 1024);

  k_zero<<<1, 256, 0, stream>>>((float*)ws);
  k_pred_fill<<<N_PTS / 256, 256, 0, stream>>>(x, cc, fill_acc, pred_x);
  k_scatter<<<K_CL * 2, 1024, 0, stream>>>(pred_x, pred_t, idx_x, idx_t,
                                           count_x, count_t);
  // W1 classes (disjoint by m): wave (m<=1024, no LDS/barriers),
  // mid (1024<m<=2048, 1 LDS phase), big (m>2048, adaptive P, <=12 barriers).
  k_w1_wave<<<K_CL * DIM / 4, 256, 0, stream>>>(
      x, target, idx_x, idx_t, count_x, count_t, parts);
  k_w1_mid<<<K_CL * DIM, 128, 0, stream>>>(
      x, target, idx_x, idx_t, count_x, count_t, parts);
  k_w1_big<<<K_CL * DIM, 512, 0, stream>>>(
      x, target, idx_x, idx_t, count_x, count_t, parts);
  k_final<<<1, 1024, 0, stream>>>(fill_acc, ft, parts, out);
}